// Round 15
// baseline (192.620 us; speedup 1.0000x reference)
//
#include <hip/hip_runtime.h>
#include <hip/hip_bf16.h>
#include <stdint.h>

typedef short bf16x8 __attribute__((ext_vector_type(8)));
typedef float f32x4 __attribute__((ext_vector_type(4)));
typedef unsigned short u16;
typedef unsigned short u16x4 __attribute__((ext_vector_type(4)));
typedef unsigned short u16x8 __attribute__((ext_vector_type(8)));
typedef unsigned int u32x4v __attribute__((ext_vector_type(4)));

#define LOG2E 1.44269504088896f

// sizes
#define Bz 4
#define Sz 2048
#define Hz 1024
#define NHz 16
#define HDz 64

__device__ __forceinline__ u16 f2bf(float f) {
  uint32_t u = __builtin_bit_cast(uint32_t, f);
  u += 0x7fffu + ((u >> 16) & 1u);
  return (u16)(u >> 16);
}
__device__ __forceinline__ float bf2f(u16 h) {
  uint32_t u = ((uint32_t)h) << 16;
  return __builtin_bit_cast(float, u);
}

__device__ __forceinline__ void gll16(const void* g, void* l) {
  __builtin_amdgcn_global_load_lds((const __attribute__((address_space(1))) void*)g,
                                   (__attribute__((address_space(3))) void*)l,
                                   16, 0, 0);
}

// ---------------- X (f32) -> bf16 ----------------
__global__ void k_cvt_x(const float* __restrict__ X, u16* __restrict__ Xb) {
  int i = blockIdx.x * 256 + threadIdx.x;
  float4 v = ((const float4*)X)[i];
  u16x4 r;
  r[0] = f2bf(v.x); r[1] = f2bf(v.y); r[2] = f2bf(v.z); r[3] = f2bf(v.w);
  ((u16x4*)Xb)[i] = r;
}

// ------- pack & transpose [Wq|Wk|Wv|Ws] -> Wt[3200][1024] bf16 -------
__global__ void k_cvt_w(const float* __restrict__ Wq, const float* __restrict__ Wk,
                        const float* __restrict__ Wv, const float* __restrict__ Ws,
                        u16* __restrict__ Wt) {
  __shared__ float tile[64][65];
  int n0 = blockIdx.x * 64, k0 = blockIdx.y * 64;
  const float* src; int ld, c0;
  if (n0 < 1024)      { src = Wq; ld = 1024; c0 = n0; }
  else if (n0 < 2048) { src = Wk; ld = 1024; c0 = n0 - 1024; }
  else if (n0 < 3072) { src = Wv; ld = 1024; c0 = n0 - 2048; }
  else                { src = Ws; ld = 128;  c0 = n0 - 3072; }
  int t = threadIdx.x;
  #pragma unroll
  for (int i = 0; i < 16; ++i) {
    int idx = t + i * 256; int r = idx >> 6, c = idx & 63;
    tile[r][c] = src[(size_t)(k0 + r) * ld + c0 + c];
  }
  __syncthreads();
  #pragma unroll
  for (int i = 0; i < 16; ++i) {
    int idx = t + i * 256; int rn = idx >> 6, ck = idx & 63;
    Wt[(size_t)(n0 + rn) * 1024 + k0 + ck] = f2bf(tile[ck][rn]);
  }
}

// ---------------- fused QKV+S GEMM: [8192,1024] x [1024,3200] ----------------
// 128x128 tile, BK=64, DBUF 64KB LDS (2 blk/CU = 16 waves/CU, same measured
// occupancy as R11's single-buf). 512 thr, 8 waves as 2M x 4N. Counted-vmcnt
// pipeline: per K-tile issue A(t+1) -> vmcnt(2) [keeps new loads in flight,
// drains only tile t's 4] -> raw s_barrier -> phaseA(MFMA) -> issue B(t+1)
// -> phaseB -> raw s_barrier. Never vmcnt(0) in loop. XCD-aware mapping.
__launch_bounds__(512, 4)
__global__ void k_gemm(const u16* __restrict__ Xb, const u16* __restrict__ Wt,
                       const float* __restrict__ bq, const float* __restrict__ bk,
                       const float* __restrict__ bv, const float* __restrict__ bs,
                       u16* __restrict__ Qw, u16* __restrict__ Kw, u16* __restrict__ Vw,
                       float* __restrict__ Sw) {
  __shared__ u16 As[2][128 * 64];   // 16KB each
  __shared__ u16 Bs[2][128 * 64];
  int t = threadIdx.x, lane = t & 63;
  int l15 = lane & 15, g = lane >> 4;
  int wave = t >> 6, wr = wave >> 2, wc = wave & 3;

  int p = blockIdx.x;
  int xcd = p & 7;
  int idx = p >> 3;            // 0..199
  int n_t = idx >> 3;          // 0..24
  int m_t = xcd * 8 + (idx & 7);
  int m0 = m_t * 128, n0 = n_t * 128;

  f32x4 acc[4][2];
  #pragma unroll
  for (int i = 0; i < 4; ++i)
    #pragma unroll
    for (int j = 0; j < 2; ++j) { f32x4 z = {0.f,0.f,0.f,0.f}; acc[i][j] = z; }

  int srow = t >> 3;               // 0..63
  int sob  = (t & 7) << 4;         // 0..112

  const char* Ag = (const char*)Xb;
  const char* Bg = (const char*)Wt;

  // each: 2 gll16/thread
  auto stageA = [&](int kt, int buf) {
    size_t kb = (size_t)kt * 128;
    #pragma unroll
    for (int c = 0; c < 2; ++c) {
      int row = c * 64 + srow;
      int sb = sob ^ ((row & 7) << 4);
      gll16(Ag + (size_t)(m0 + row) * 2048 + kb + sb, (char*)As[buf] + row * 128 + sob);
    }
  };
  auto stageB = [&](int kt, int buf) {
    size_t kb = (size_t)kt * 128;
    #pragma unroll
    for (int c = 0; c < 2; ++c) {
      int row = c * 64 + srow;
      int sb = sob ^ ((row & 7) << 4);
      gll16(Bg + (size_t)(n0 + row) * 2048 + kb + sb, (char*)Bs[buf] + row * 128 + sob);
    }
  };

  // prologue: tile 0 into buf 0, full drain once
  stageA(0, 0);
  stageB(0, 0);
  asm volatile("s_waitcnt vmcnt(0)" ::: "memory");
  __builtin_amdgcn_s_barrier();
  __builtin_amdgcn_sched_barrier(0);

  for (int kt = 0; kt < 16; ++kt) {
    int cur = kt & 1;
    // issue next tile's A into the other buffer (read-done guaranteed by the
    // barrier at the end of tile kt-1)
    if (kt + 1 < 16) {
      stageA(kt + 1, cur ^ 1);
      // outstanding = 4 (tile kt) + 2 (A next) -> drain tile kt's, keep 2
      asm volatile("s_waitcnt vmcnt(2)" ::: "memory");
    } else if (kt > 0) {
      asm volatile("s_waitcnt vmcnt(0)" ::: "memory");
    }
    __builtin_amdgcn_sched_barrier(0);
    __builtin_amdgcn_s_barrier();   // buf[cur] fully staged for ALL threads
    __builtin_amdgcn_sched_barrier(0);

    const char* Ab = (const char*)As[cur];
    const char* Bb = (const char*)Bs[cur];

    // ---- phase A: ksub 0 ----
    {
      bf16x8 af[4], bfr[2];
      #pragma unroll
      for (int ai = 0; ai < 4; ++ai) {
        int row = wr * 64 + ai * 16 + l15;
        af[ai] = *(const bf16x8*)(Ab + row * 128 + ((16 * g) ^ ((row & 7) << 4)));
      }
      #pragma unroll
      for (int bj = 0; bj < 2; ++bj) {
        int row = wc * 32 + bj * 16 + l15;
        bfr[bj] = *(const bf16x8*)(Bb + row * 128 + ((16 * g) ^ ((row & 7) << 4)));
      }
      __builtin_amdgcn_s_setprio(1);
      #pragma unroll
      for (int ai = 0; ai < 4; ++ai)
        #pragma unroll
        for (int bj = 0; bj < 2; ++bj)
          acc[ai][bj] = __builtin_amdgcn_mfma_f32_16x16x32_bf16(af[ai], bfr[bj], acc[ai][bj], 0, 0, 0);
      __builtin_amdgcn_s_setprio(0);
    }
    // issue next tile's B (overlaps phase B compute)
    if (kt + 1 < 16) stageB(kt + 1, cur ^ 1);
    // ---- phase B: ksub 1 ----
    {
      bf16x8 af[4], bfr[2];
      #pragma unroll
      for (int ai = 0; ai < 4; ++ai) {
        int row = wr * 64 + ai * 16 + l15;
        af[ai] = *(const bf16x8*)(Ab + row * 128 + ((64 + 16 * g) ^ ((row & 7) << 4)));
      }
      #pragma unroll
      for (int bj = 0; bj < 2; ++bj) {
        int row = wc * 32 + bj * 16 + l15;
        bfr[bj] = *(const bf16x8*)(Bb + row * 128 + ((64 + 16 * g) ^ ((row & 7) << 4)));
      }
      __builtin_amdgcn_s_setprio(1);
      #pragma unroll
      for (int ai = 0; ai < 4; ++ai)
        #pragma unroll
        for (int bj = 0; bj < 2; ++bj)
          acc[ai][bj] = __builtin_amdgcn_mfma_f32_16x16x32_bf16(af[ai], bfr[bj], acc[ai][bj], 0, 0, 0);
      __builtin_amdgcn_s_setprio(0);
    }
    __builtin_amdgcn_sched_barrier(0);
    __builtin_amdgcn_s_barrier();   // all waves done reading buf[cur]
    __builtin_amdgcn_sched_barrier(0);
  }

  #pragma unroll
  for (int ai = 0; ai < 4; ++ai) {
    #pragma unroll
    for (int bj = 0; bj < 2; ++bj) {
      #pragma unroll
      for (int r = 0; r < 4; ++r) {
        int m = m0 + wr * 64 + ai * 16 + ((lane >> 4) << 2) + r;
        int j = n0 + wc * 32 + bj * 16 + l15;
        float v = acc[ai][bj][r];
        int b = m >> 11, si = m & 2047;
        if (j < 3072) {
          float bias = (j < 1024) ? bq[j] : (j < 2048) ? bk[j - 1024] : bv[j - 2048];
          v += bias;
          int jj = j & 1023, h = jj >> 6, d = jj & 63;
          size_t dst = (((size_t)(b * NHz + h) * Sz + si) << 6) + d;
          u16 hv = f2bf(v);
          if (j < 1024) Qw[dst] = hv;
          else if (j < 2048) Kw[dst] = hv;
          else Vw[dst] = hv;
        } else {
          int c = j - 3072;
          v += bs[c];
          float sig = 1.0f / (1.0f + __expf(-v));
          // fold softmax 1/sqrt(64) AND log2(e) (exp->exp2 domain) into Q scale
          Sw[(size_t)m * 128 + c] = (0.9f + 0.2f * sig) * 0.125f * LOG2E;
        }
      }
    }
  }
}

// ---------------- fallback: Q *= s (only if ws can't hold Sw) ----------------
__global__ void k_scale_q(u16* __restrict__ Qw, const float* __restrict__ Sw) {
  int tid = blockIdx.x * 256 + threadIdx.x;
  size_t base = (size_t)tid * 8;
  int bh = (int)(base >> 17);
  int si = (int)((base >> 6) & 2047);
  int d0 = (int)(base & 63);
  int b = bh >> 4, h = bh & 15;
  float s = Sw[((size_t)(b * Sz + si)) * 128 + h * 8 + (d0 >> 3)];
  u16x8 v = *(u16x8*)(Qw + base);
  #pragma unroll
  for (int j = 0; j < 8; ++j) v[j] = f2bf(bf2f(v[j]) * s);
  *(u16x8*)(Qw + base) = v;
}

// ---------------- V [bh][s][d] -> Vt [bh][d][s] ----------------
__global__ void k_trans_v(const u16* __restrict__ Vw, u16* __restrict__ Vt) {
  __shared__ u16 tile[64][65];
  int bh = blockIdx.y, s0 = blockIdx.x * 64;
  int t = threadIdx.x;
  const u16* src = Vw + ((size_t)bh * Sz + s0) * 64;
  #pragma unroll
  for (int i = 0; i < 16; ++i) {
    int idx = t + i * 256; int r = idx >> 6, c = idx & 63;
    tile[r][c] = src[r * 64 + c];
  }
  __syncthreads();
  u16* dst = Vt + (size_t)bh * 64 * Sz;
  #pragma unroll
  for (int i = 0; i < 16; ++i) {
    int idx = t + i * 256; int d = idx >> 6, ss = idx & 63;
    dst[(size_t)d * Sz + s0 + ss] = tile[ss][d];
  }
}

// ---------------- attention: qi=4 (QBLK=64/wave) + in-register P (T12) ----------------
// grid (64 bh, 8 q-blocks of 256). 4 waves x 64 q-rows; KVBLK=64, dbuf K/V (32KB).
// Swapped QK^T with pi-permuted K rows; exp2 no-max; P C->A relayout fully
// in-register via cvt_pk + v_permlane32_swap_b32; row-sums via ones-MFMA.
__launch_bounds__(256)
__global__ void k_attn(const u16* __restrict__ Qw, const u16* __restrict__ Kw,
                       const u16* __restrict__ Vt, const float* __restrict__ Swp,
                       float* __restrict__ out) {
  __shared__ u16 Kl[2][64 * 64];   // 16KB
  __shared__ u16 Vl[2][64 * 64];   // 16KB

  int t = threadIdx.x, lane = t & 63, wave = t >> 6;
  int l15 = lane & 15, g = lane >> 4;
  int bh = blockIdx.x, b = bh >> 4, h = bh & 15;
  int q0 = blockIdx.y * 256 + wave * 64;

  const u16* Qb = Qw + (size_t)bh * Sz * 64;
  const char* Kg = (const char*)(Kw + (size_t)bh * Sz * 64);
  const char* Vg = (const char*)(Vt + (size_t)bh * 64 * Sz);

  // pi(l15): swap bits 2 and 3 (loop-invariant)
  int pi15 = (l15 & 3) | ((l15 & 4) << 1) | ((l15 & 8) >> 1);

  int srow = t >> 3;               // 0..31
  int sobyte = (t & 7) << 4;       // 0..112

  bf16x8 qf[4][2];
  #pragma unroll
  for (int qi = 0; qi < 4; ++qi)
    #pragma unroll
    for (int ks = 0; ks < 2; ++ks)
      qf[qi][ks] = *(const bf16x8*)(Qb + (size_t)(q0 + 16 * qi + l15) * 64 + 32 * ks + 8 * g);
  if (Swp) {
    #pragma unroll
    for (int qi = 0; qi < 4; ++qi) {
      size_t m = (size_t)(b * Sz + q0 + 16 * qi + l15);
      #pragma unroll
      for (int ks = 0; ks < 2; ++ks) {
        float s = Swp[m * 128 + h * 8 + 4 * ks + g];
        bf16x8 q = qf[qi][ks];
        #pragma unroll
        for (int j = 0; j < 8; ++j) q[j] = (short)f2bf(bf2f((u16)q[j]) * s);
        qf[qi][ks] = q;
      }
    }
  }

  bf16x8 ones;
  #pragma unroll
  for (int j = 0; j < 8; ++j) ones[j] = (short)0x3F80;

  f32x4 o[4][4], lacc[4];
  #pragma unroll
  for (int qi = 0; qi < 4; ++qi) {
    f32x4 z = {0.f,0.f,0.f,0.f};
    lacc[qi] = z;
    #pragma unroll
    for (int nt = 0; nt < 4; ++nt) o[qi][nt] = z;
  }

  // prologue: stage tile 0 into buf 0 (4 gll16/thread)
  #pragma unroll
  for (int c = 0; c < 2; ++c) {
    int row = c * 32 + srow;
    int sw2 = (row & 7) << 4;
    gll16(Kg + (size_t)row * 128 + (sobyte ^ sw2), (char*)Kl[0] + row * 128 + sobyte);
    gll16(Vg + (size_t)row * (Sz * 2) + (sobyte ^ sw2), (char*)Vl[0] + row * 128 + sobyte);
  }
  __syncthreads();

  int cur = 0;
  for (int kv0 = 0; kv0 < Sz; kv0 += 64) {
    if (kv0 + 64 < Sz) {
      int nxt = cur ^ 1, kvn = kv0 + 64;
      #pragma unroll
      for (int c = 0; c < 2; ++c) {
        int row = c * 32 + srow;
        int sw2 = (row & 7) << 4;
        gll16(Kg + (size_t)(kvn + row) * 128 + (sobyte ^ sw2),
              (char*)Kl[nxt] + row * 128 + sobyte);
        gll16(Vg + (size_t)row * (Sz * 2) + (size_t)kvn * 2 + (sobyte ^ sw2),
              (char*)Vl[nxt] + row * 128 + sobyte);
      }
    }
    const char* Kb = (const char*)Kl[cur];
    const char* Vb = (const char*)Vl[cur];

    // ---- per qi-pair: QK^T (swapped, pi-permuted) + exp2 + in-reg relayout ----
    bf16x8 pa[4][2];
    #pragma unroll
    for (int qp = 0; qp < 2; ++qp) {
      f32x4 sc[2][4];
      __builtin_amdgcn_s_setprio(1);
      #pragma unroll
      for (int nt = 0; nt < 4; ++nt) {
        int row = 16 * nt + pi15;
        int sw2 = (row & 7) << 4;
        bf16x8 kf0 = *(const bf16x8*)(Kb + row * 128 + ((16 * g) ^ sw2));
        bf16x8 kf1 = *(const bf16x8*)(Kb + row * 128 + ((64 + 16 * g) ^ sw2));
        #pragma unroll
        for (int j = 0; j < 2; ++j) {
          f32x4 a = {0.f,0.f,0.f,0.f};
          a = __builtin_amdgcn_mfma_f32_16x16x32_bf16(kf0, qf[2 * qp + j][0], a, 0, 0, 0);
          a = __builtin_amdgcn_mfma_f32_16x16x32_bf16(kf1, qf[2 * qp + j][1], a, 0, 0, 0);
          sc[j][nt] = a;
        }
      }
      __builtin_amdgcn_s_setprio(0);
      #pragma unroll
      for (int j = 0; j < 2; ++j) {
        unsigned W0[4], W1[4];
        #pragma unroll
        for (int nt = 0; nt < 4; ++nt) {
          float p0 = __builtin_amdgcn_exp2f(sc[j][nt][0]);
          float p1 = __builtin_amdgcn_exp2f(sc[j][nt][1]);
          float p2 = __builtin_amdgcn_exp2f(sc[j][nt][2]);
          float p3 = __builtin_amdgcn_exp2f(sc[j][nt][3]);
          asm("v_cvt_pk_bf16_f32 %0, %1, %2" : "=v"(W0[nt]) : "v"(p0), "v"(p1));
          asm("v_cvt_pk_bf16_f32 %0, %1, %2" : "=v"(W1[nt]) : "v"(p2), "v"(p3));
        }
        #pragma unroll
        for (int ks = 0; ks < 2; ++ks) {
          unsigned x0 = W0[2 * ks], y0 = W0[2 * ks + 1];
          unsigned x1 = W1[2 * ks], y1 = W1[2 * ks + 1];
          // dst' = {dst.row0, src.row0}; src' = {dst.row1, src.row1}
          asm("v_permlane32_swap_b32 %0, %1" : "+v"(x0), "+v"(y0));
          asm("v_permlane32_swap_b32 %0, %1" : "+v"(x1), "+v"(y1));
          u32x4v wv; wv[0] = x0; wv[1] = x1; wv[2] = y0; wv[3] = y1;
          pa[2 * qp + j][ks] = __builtin_bit_cast(bf16x8, wv);
        }
      }
    }

    // ---- PV + row-sum: single pass, vf read once per (ks,nt) ----
    __builtin_amdgcn_s_setprio(1);
    #pragma unroll
    for (int ks = 0; ks < 2; ++ks) {
      #pragma unroll
      for (int qi = 0; qi < 4; ++qi)
        lacc[qi] = __builtin_amdgcn_mfma_f32_16x16x32_bf16(pa[qi][ks], ones, lacc[qi], 0, 0, 0);
      #pragma unroll
      for (int nt = 0; nt < 4; ++nt) {
        int row = 16 * nt + l15;
        int sw2 = (row & 7) << 4;
        bf16x8 vf = *(const bf16x8*)(Vb + row * 128 + ((64 * ks + 16 * g) ^ sw2));
        #pragma unroll
        for (int qi = 0; qi < 4; ++qi)
          o[qi][nt] = __builtin_amdgcn_mfma_f32_16x16x32_bf16(pa[qi][ks], vf, o[qi][nt], 0, 0, 0);
      }
    }
    __builtin_amdgcn_s_setprio(0);
    __syncthreads();
    cur ^= 1;
  }

  // ---- epilogue: out = o / rowsum (lacc has same C-layout as o) ----
  #pragma unroll
  for (int qi = 0; qi < 4; ++qi) {
    #pragma unroll
    for (int r = 0; r < 4; ++r) {
      float inv = 1.0f / lacc[qi][r];
      #pragma unroll
      for (int nt = 0; nt < 4; ++nt)
        out[((size_t)(b * Sz + q0 + 16 * qi + 4 * g + r)) * (NHz * HDz) +
            h * 64 + 16 * nt + l15] = o[qi][nt][r] * inv;
    }
  }
}

extern "C" void kernel_launch(void* const* d_in, const int* in_sizes, int n_in,
                              void* d_out, int out_size, void* d_ws, size_t ws_size,
                              hipStream_t stream) {
  const float* X  = (const float*)d_in[0];
  const float* Wq = (const float*)d_in[1];
  const float* bq = (const float*)d_in[2];
  const float* Wk = (const float*)d_in[3];
  const float* bk = (const float*)d_in[4];
  const float* Wv = (const float*)d_in[5];
  const float* bv = (const float*)d_in[6];
  const float* Ws = (const float*)d_in[7];
  const float* bs = (const float*)d_in[8];
  float* out = (float*)d_out;

  // ws: Qw | Kw | Vw | Vt (16 MB each) [+ Sw 4MB if room]
  char* ws = (char*)d_ws;
  u16* Qw = (u16*)(ws);
  u16* Kw = (u16*)(ws + (size_t)(16u << 20));
  u16* Vw = (u16*)(ws + (size_t)(32u << 20));
  u16* Vt = (u16*)(ws + (size_t)(48u << 20));

  // d_out scratch: Xb (16MB) | Wt (6.55MB) — consumed by k_gemm before attn writes.
  char* ob = (char*)d_out;
  u16* Xb   = (u16*)ob;
  u16* Wt   = (u16*)(ob + (size_t)(16u << 20));

  bool fused = ws_size >= ((size_t)(64u << 20) + (size_t)(4u << 20));
  float* Sw = fused ? (float*)(ws + (size_t)(64u << 20))
                    : (float*)(ob + (size_t)(24u << 20));  // fallback: consumed pre-attn

  k_cvt_x<<<8192, 256, 0, stream>>>(X, Xb);
  k_cvt_w<<<dim3(50, 16), 256, 0, stream>>>(Wq, Wk, Wv, Ws, Wt);
  k_gemm<<<1600, 512, 0, stream>>>(Xb, Wt, bq, bk, bv, bs, Qw, Kw, Vw, Sw);
  if (!fused) k_scale_q<<<4096, 256, 0, stream>>>(Qw, Sw);
  k_trans_v<<<dim3(32, 64), 256, 0, stream>>>(Vw, Vt);
  k_attn<<<dim3(64, 8), 256, 0, stream>>>(Qw, Kw, Vt, fused ? Sw : nullptr, out);
}

// Round 16
// 180.630 us; speedup vs baseline: 1.0664x; 1.0664x over previous
//
#include <hip/hip_runtime.h>
#include <hip/hip_bf16.h>
#include <stdint.h>

typedef short bf16x8 __attribute__((ext_vector_type(8)));
typedef float f32x4 __attribute__((ext_vector_type(4)));
typedef unsigned short u16;
typedef unsigned short u16x4 __attribute__((ext_vector_type(4)));
typedef unsigned short u16x8 __attribute__((ext_vector_type(8)));
typedef unsigned int u32x4v __attribute__((ext_vector_type(4)));

#define LOG2E 1.44269504088896f

// sizes
#define Bz 4
#define Sz 2048
#define Hz 1024
#define NHz 16
#define HDz 64

__device__ __forceinline__ u16 f2bf(float f) {
  uint32_t u = __builtin_bit_cast(uint32_t, f);
  u += 0x7fffu + ((u >> 16) & 1u);
  return (u16)(u >> 16);
}
__device__ __forceinline__ float bf2f(u16 h) {
  uint32_t u = ((uint32_t)h) << 16;
  return __builtin_bit_cast(float, u);
}

__device__ __forceinline__ void gll16(const void* g, void* l) {
  __builtin_amdgcn_global_load_lds((const __attribute__((address_space(1))) void*)g,
                                   (__attribute__((address_space(3))) void*)l,
                                   16, 0, 0);
}

// ---------------- X (f32) -> bf16 ----------------
__global__ void k_cvt_x(const float* __restrict__ X, u16* __restrict__ Xb) {
  int i = blockIdx.x * 256 + threadIdx.x;
  float4 v = ((const float4*)X)[i];
  u16x4 r;
  r[0] = f2bf(v.x); r[1] = f2bf(v.y); r[2] = f2bf(v.z); r[3] = f2bf(v.w);
  ((u16x4*)Xb)[i] = r;
}

// ------- pack & transpose [Wq|Wk|Wv|Ws] -> Wt[3200][1024] bf16 -------
__global__ void k_cvt_w(const float* __restrict__ Wq, const float* __restrict__ Wk,
                        const float* __restrict__ Wv, const float* __restrict__ Ws,
                        u16* __restrict__ Wt) {
  __shared__ float tile[64][65];
  int n0 = blockIdx.x * 64, k0 = blockIdx.y * 64;
  const float* src; int ld, c0;
  if (n0 < 1024)      { src = Wq; ld = 1024; c0 = n0; }
  else if (n0 < 2048) { src = Wk; ld = 1024; c0 = n0 - 1024; }
  else if (n0 < 3072) { src = Wv; ld = 1024; c0 = n0 - 2048; }
  else                { src = Ws; ld = 128;  c0 = n0 - 3072; }
  int t = threadIdx.x;
  #pragma unroll
  for (int i = 0; i < 16; ++i) {
    int idx = t + i * 256; int r = idx >> 6, c = idx & 63;
    tile[r][c] = src[(size_t)(k0 + r) * ld + c0 + c];
  }
  __syncthreads();
  #pragma unroll
  for (int i = 0; i < 16; ++i) {
    int idx = t + i * 256; int rn = idx >> 6, ck = idx & 63;
    Wt[(size_t)(n0 + rn) * 1024 + k0 + ck] = f2bf(tile[ck][rn]);
  }
}

// ---------------- fused QKV+S GEMM: [8192,1024] x [1024,3200] ----------------
// 128x128 tile, BK=64, single-buffer 32KB LDS -> 3 blk/CU; 512 thr (2Mx4N waves);
// XCD-aware bijective mapping (each XCD owns an 8-m-tile row).
// BEST MEASURED CONFIG (R11): 96.5us, MfmaUtil 23, Occ 50. Five structural
// experiments (bigger tiles, 256thr, dbuf+counted-vmcnt) all regressed -> the
// 2-phase family is at its ceiling here; keep this.
__launch_bounds__(512, 6)
__global__ void k_gemm(const u16* __restrict__ Xb, const u16* __restrict__ Wt,
                       const float* __restrict__ bq, const float* __restrict__ bk,
                       const float* __restrict__ bv, const float* __restrict__ bs,
                       u16* __restrict__ Qw, u16* __restrict__ Kw, u16* __restrict__ Vw,
                       float* __restrict__ Sw) {
  __shared__ u16 As[128 * 64];   // 16KB
  __shared__ u16 Bs[128 * 64];
  int t = threadIdx.x, lane = t & 63;
  int l15 = lane & 15, g = lane >> 4;
  int wave = t >> 6, wr = wave >> 2, wc = wave & 3;

  int p = blockIdx.x;
  int xcd = p & 7;
  int idx = p >> 3;            // 0..199
  int n_t = idx >> 3;          // 0..24
  int m_t = xcd * 8 + (idx & 7);
  int m0 = m_t * 128, n0 = n_t * 128;

  f32x4 acc[4][2];
  #pragma unroll
  for (int i = 0; i < 4; ++i)
    #pragma unroll
    for (int j = 0; j < 2; ++j) { f32x4 z = {0.f,0.f,0.f,0.f}; acc[i][j] = z; }

  int srow = t >> 3;               // 0..63
  int sob  = (t & 7) << 4;         // 0..112

  const char* Ag = (const char*)Xb;
  const char* Bg = (const char*)Wt;

  {
    int row = srow;
    int sb = sob ^ ((row & 7) << 4);
    gll16(Ag + (size_t)(m0 + row) * 2048 + sb, (char*)As + row * 128 + sob);
    gll16(Bg + (size_t)(n0 + row) * 2048 + sb, (char*)Bs + row * 128 + sob);
    row = 64 + srow;
    sb = sob ^ ((row & 7) << 4);
    gll16(Ag + (size_t)(m0 + row) * 2048 + sb, (char*)As + row * 128 + sob);
    gll16(Bg + (size_t)(n0 + row) * 2048 + sb, (char*)Bs + row * 128 + sob);
  }
  __syncthreads();

  for (int kt = 0; kt < 16; ++kt) {
    #pragma unroll
    for (int ksub = 0; ksub < 2; ++ksub) {
      bf16x8 af[4], bfr[2];
      #pragma unroll
      for (int ai = 0; ai < 4; ++ai) {
        int row = wr * 64 + ai * 16 + l15;
        af[ai] = *(const bf16x8*)((const char*)As + row * 128 +
                                  ((ksub * 64 + 16 * g) ^ ((row & 7) << 4)));
      }
      #pragma unroll
      for (int bj = 0; bj < 2; ++bj) {
        int row = wc * 32 + bj * 16 + l15;
        bfr[bj] = *(const bf16x8*)((const char*)Bs + row * 128 +
                                   ((ksub * 64 + 16 * g) ^ ((row & 7) << 4)));
      }
      #pragma unroll
      for (int ai = 0; ai < 4; ++ai)
        #pragma unroll
        for (int bj = 0; bj < 2; ++bj)
          acc[ai][bj] = __builtin_amdgcn_mfma_f32_16x16x32_bf16(af[ai], bfr[bj], acc[ai][bj], 0, 0, 0);
    }
    if (kt + 1 < 16) {
      __syncthreads();
      size_t kb = (size_t)(kt + 1) * 128;
      int row = srow;
      int sb = sob ^ ((row & 7) << 4);
      gll16(Ag + (size_t)(m0 + row) * 2048 + kb + sb, (char*)As + row * 128 + sob);
      gll16(Bg + (size_t)(n0 + row) * 2048 + kb + sb, (char*)Bs + row * 128 + sob);
      row = 64 + srow;
      sb = sob ^ ((row & 7) << 4);
      gll16(Ag + (size_t)(m0 + row) * 2048 + kb + sb, (char*)As + row * 128 + sob);
      gll16(Bg + (size_t)(n0 + row) * 2048 + kb + sb, (char*)Bs + row * 128 + sob);
      __syncthreads();
    }
  }

  #pragma unroll
  for (int ai = 0; ai < 4; ++ai) {
    #pragma unroll
    for (int bj = 0; bj < 2; ++bj) {
      #pragma unroll
      for (int r = 0; r < 4; ++r) {
        int m = m0 + wr * 64 + ai * 16 + ((lane >> 4) << 2) + r;
        int j = n0 + wc * 32 + bj * 16 + l15;
        float v = acc[ai][bj][r];
        int b = m >> 11, si = m & 2047;
        if (j < 3072) {
          float bias = (j < 1024) ? bq[j] : (j < 2048) ? bk[j - 1024] : bv[j - 2048];
          v += bias;
          int jj = j & 1023, h = jj >> 6, d = jj & 63;
          size_t dst = (((size_t)(b * NHz + h) * Sz + si) << 6) + d;
          u16 hv = f2bf(v);
          if (j < 1024) Qw[dst] = hv;
          else if (j < 2048) Kw[dst] = hv;
          else Vw[dst] = hv;
        } else {
          int c = j - 3072;
          v += bs[c];
          float sig = 1.0f / (1.0f + __expf(-v));
          // fold softmax 1/sqrt(64) AND log2(e) (exp->exp2 domain) into Q scale
          Sw[(size_t)m * 128 + c] = (0.9f + 0.2f * sig) * 0.125f * LOG2E;
        }
      }
    }
  }
}

// ---------------- fallback: Q *= s (only if ws can't hold Sw) ----------------
__global__ void k_scale_q(u16* __restrict__ Qw, const float* __restrict__ Sw) {
  int tid = blockIdx.x * 256 + threadIdx.x;
  size_t base = (size_t)tid * 8;
  int bh = (int)(base >> 17);
  int si = (int)((base >> 6) & 2047);
  int d0 = (int)(base & 63);
  int b = bh >> 4, h = bh & 15;
  float s = Sw[((size_t)(b * Sz + si)) * 128 + h * 8 + (d0 >> 3)];
  u16x8 v = *(u16x8*)(Qw + base);
  #pragma unroll
  for (int j = 0; j < 8; ++j) v[j] = f2bf(bf2f(v[j]) * s);
  *(u16x8*)(Qw + base) = v;
}

// ---------------- V [bh][s][d] -> Vt [bh][d][s] ----------------
__global__ void k_trans_v(const u16* __restrict__ Vw, u16* __restrict__ Vt) {
  __shared__ u16 tile[64][65];
  int bh = blockIdx.y, s0 = blockIdx.x * 64;
  int t = threadIdx.x;
  const u16* src = Vw + ((size_t)bh * Sz + s0) * 64;
  #pragma unroll
  for (int i = 0; i < 16; ++i) {
    int idx = t + i * 256; int r = idx >> 6, c = idx & 63;
    tile[r][c] = src[r * 64 + c];
  }
  __syncthreads();
  u16* dst = Vt + (size_t)bh * 64 * Sz;
  #pragma unroll
  for (int i = 0; i < 16; ++i) {
    int idx = t + i * 256; int d = idx >> 6, ss = idx & 63;
    dst[(size_t)d * Sz + s0 + ss] = tile[ss][d];
  }
}

// ---------------- attention: qi=4 (QBLK=64/wave) + in-register P (T12) ----------------
// grid (64 bh, 8 q-blocks of 256). 4 waves x 64 q-rows; KVBLK=64, dbuf K/V (32KB).
// Swapped QK^T with pi-permuted K rows; exp2 no-max; P C->A relayout fully
// in-register via cvt_pk + v_permlane32_swap_b32; row-sums via ones-MFMA.
__launch_bounds__(256)
__global__ void k_attn(const u16* __restrict__ Qw, const u16* __restrict__ Kw,
                       const u16* __restrict__ Vt, const float* __restrict__ Swp,
                       float* __restrict__ out) {
  __shared__ u16 Kl[2][64 * 64];   // 16KB
  __shared__ u16 Vl[2][64 * 64];   // 16KB

  int t = threadIdx.x, lane = t & 63, wave = t >> 6;
  int l15 = lane & 15, g = lane >> 4;
  int bh = blockIdx.x, b = bh >> 4, h = bh & 15;
  int q0 = blockIdx.y * 256 + wave * 64;

  const u16* Qb = Qw + (size_t)bh * Sz * 64;
  const char* Kg = (const char*)(Kw + (size_t)bh * Sz * 64);
  const char* Vg = (const char*)(Vt + (size_t)bh * 64 * Sz);

  // pi(l15): swap bits 2 and 3 (loop-invariant)
  int pi15 = (l15 & 3) | ((l15 & 4) << 1) | ((l15 & 8) >> 1);

  int srow = t >> 3;               // 0..31
  int sobyte = (t & 7) << 4;       // 0..112

  bf16x8 qf[4][2];
  #pragma unroll
  for (int qi = 0; qi < 4; ++qi)
    #pragma unroll
    for (int ks = 0; ks < 2; ++ks)
      qf[qi][ks] = *(const bf16x8*)(Qb + (size_t)(q0 + 16 * qi + l15) * 64 + 32 * ks + 8 * g);
  if (Swp) {
    #pragma unroll
    for (int qi = 0; qi < 4; ++qi) {
      size_t m = (size_t)(b * Sz + q0 + 16 * qi + l15);
      #pragma unroll
      for (int ks = 0; ks < 2; ++ks) {
        float s = Swp[m * 128 + h * 8 + 4 * ks + g];
        bf16x8 q = qf[qi][ks];
        #pragma unroll
        for (int j = 0; j < 8; ++j) q[j] = (short)f2bf(bf2f((u16)q[j]) * s);
        qf[qi][ks] = q;
      }
    }
  }

  bf16x8 ones;
  #pragma unroll
  for (int j = 0; j < 8; ++j) ones[j] = (short)0x3F80;

  f32x4 o[4][4], lacc[4];
  #pragma unroll
  for (int qi = 0; qi < 4; ++qi) {
    f32x4 z = {0.f,0.f,0.f,0.f};
    lacc[qi] = z;
    #pragma unroll
    for (int nt = 0; nt < 4; ++nt) o[qi][nt] = z;
  }

  // prologue: stage tile 0 into buf 0 (4 gll16/thread)
  #pragma unroll
  for (int c = 0; c < 2; ++c) {
    int row = c * 32 + srow;
    int sw2 = (row & 7) << 4;
    gll16(Kg + (size_t)row * 128 + (sobyte ^ sw2), (char*)Kl[0] + row * 128 + sobyte);
    gll16(Vg + (size_t)row * (Sz * 2) + (sobyte ^ sw2), (char*)Vl[0] + row * 128 + sobyte);
  }
  __syncthreads();

  int cur = 0;
  for (int kv0 = 0; kv0 < Sz; kv0 += 64) {
    if (kv0 + 64 < Sz) {
      int nxt = cur ^ 1, kvn = kv0 + 64;
      #pragma unroll
      for (int c = 0; c < 2; ++c) {
        int row = c * 32 + srow;
        int sw2 = (row & 7) << 4;
        gll16(Kg + (size_t)(kvn + row) * 128 + (sobyte ^ sw2),
              (char*)Kl[nxt] + row * 128 + sobyte);
        gll16(Vg + (size_t)row * (Sz * 2) + (size_t)kvn * 2 + (sobyte ^ sw2),
              (char*)Vl[nxt] + row * 128 + sobyte);
      }
    }
    const char* Kb = (const char*)Kl[cur];
    const char* Vb = (const char*)Vl[cur];

    // ---- per qi-pair: QK^T (swapped, pi-permuted) + exp2 + in-reg relayout ----
    bf16x8 pa[4][2];
    #pragma unroll
    for (int qp = 0; qp < 2; ++qp) {
      f32x4 sc[2][4];
      __builtin_amdgcn_s_setprio(1);
      #pragma unroll
      for (int nt = 0; nt < 4; ++nt) {
        int row = 16 * nt + pi15;
        int sw2 = (row & 7) << 4;
        bf16x8 kf0 = *(const bf16x8*)(Kb + row * 128 + ((16 * g) ^ sw2));
        bf16x8 kf1 = *(const bf16x8*)(Kb + row * 128 + ((64 + 16 * g) ^ sw2));
        #pragma unroll
        for (int j = 0; j < 2; ++j) {
          f32x4 a = {0.f,0.f,0.f,0.f};
          a = __builtin_amdgcn_mfma_f32_16x16x32_bf16(kf0, qf[2 * qp + j][0], a, 0, 0, 0);
          a = __builtin_amdgcn_mfma_f32_16x16x32_bf16(kf1, qf[2 * qp + j][1], a, 0, 0, 0);
          sc[j][nt] = a;
        }
      }
      __builtin_amdgcn_s_setprio(0);
      #pragma unroll
      for (int j = 0; j < 2; ++j) {
        unsigned W0[4], W1[4];
        #pragma unroll
        for (int nt = 0; nt < 4; ++nt) {
          float p0 = __builtin_amdgcn_exp2f(sc[j][nt][0]);
          float p1 = __builtin_amdgcn_exp2f(sc[j][nt][1]);
          float p2 = __builtin_amdgcn_exp2f(sc[j][nt][2]);
          float p3 = __builtin_amdgcn_exp2f(sc[j][nt][3]);
          asm("v_cvt_pk_bf16_f32 %0, %1, %2" : "=v"(W0[nt]) : "v"(p0), "v"(p1));
          asm("v_cvt_pk_bf16_f32 %0, %1, %2" : "=v"(W1[nt]) : "v"(p2), "v"(p3));
        }
        #pragma unroll
        for (int ks = 0; ks < 2; ++ks) {
          unsigned x0 = W0[2 * ks], y0 = W0[2 * ks + 1];
          unsigned x1 = W1[2 * ks], y1 = W1[2 * ks + 1];
          // dst' = {dst.row0, src.row0}; src' = {dst.row1, src.row1}
          asm("v_permlane32_swap_b32 %0, %1" : "+v"(x0), "+v"(y0));
          asm("v_permlane32_swap_b32 %0, %1" : "+v"(x1), "+v"(y1));
          u32x4v wv; wv[0] = x0; wv[1] = x1; wv[2] = y0; wv[3] = y1;
          pa[2 * qp + j][ks] = __builtin_bit_cast(bf16x8, wv);
        }
      }
    }

    // ---- PV + row-sum: single pass, vf read once per (ks,nt) ----
    __builtin_amdgcn_s_setprio(1);
    #pragma unroll
    for (int ks = 0; ks < 2; ++ks) {
      #pragma unroll
      for (int qi = 0; qi < 4; ++qi)
        lacc[qi] = __builtin_amdgcn_mfma_f32_16x16x32_bf16(pa[qi][ks], ones, lacc[qi], 0, 0, 0);
      #pragma unroll
      for (int nt = 0; nt < 4; ++nt) {
        int row = 16 * nt + l15;
        int sw2 = (row & 7) << 4;
        bf16x8 vf = *(const bf16x8*)(Vb + row * 128 + ((64 * ks + 16 * g) ^ sw2));
        #pragma unroll
        for (int qi = 0; qi < 4; ++qi)
          o[qi][nt] = __builtin_amdgcn_mfma_f32_16x16x32_bf16(pa[qi][ks], vf, o[qi][nt], 0, 0, 0);
      }
    }
    __builtin_amdgcn_s_setprio(0);
    __syncthreads();
    cur ^= 1;
  }

  // ---- epilogue: out = o / rowsum (lacc has same C-layout as o) ----
  #pragma unroll
  for (int qi = 0; qi < 4; ++qi) {
    #pragma unroll
    for (int r = 0; r < 4; ++r) {
      float inv = 1.0f / lacc[qi][r];
      #pragma unroll
      for (int nt = 0; nt < 4; ++nt)
        out[((size_t)(b * Sz + q0 + 16 * qi + 4 * g + r)) * (NHz * HDz) +
            h * 64 + 16 * nt + l15] = o[qi][nt][r] * inv;
    }
  }
}

extern "C" void kernel_launch(void* const* d_in, const int* in_sizes, int n_in,
                              void* d_out, int out_size, void* d_ws, size_t ws_size,
                              hipStream_t stream) {
  const float* X  = (const float*)d_in[0];
  const float* Wq = (const float*)d_in[1];
  const float* bq = (const float*)d_in[2];
  const float* Wk = (const float*)d_in[3];
  const float* bk = (const float*)d_in[4];
  const float* Wv = (const float*)d_in[5];
  const float* bv = (const float*)d_in[6];
  const float* Ws = (const float*)d_in[7];
  const float* bs = (const float*)d_in[8];
  float* out = (float*)d_out;

  // ws: Qw | Kw | Vw | Vt (16 MB each) [+ Sw 4MB if room]
  char* ws = (char*)d_ws;
  u16* Qw = (u16*)(ws);
  u16* Kw = (u16*)(ws + (size_t)(16u << 20));
  u16* Vw = (u16*)(ws + (size_t)(32u << 20));
  u16* Vt = (u16*)(ws + (size_t)(48u << 20));

  // d_out scratch: Xb (16MB) | Wt (6.55MB) — consumed by k_gemm before attn writes.
  char* ob = (char*)d_out;
  u16* Xb   = (u16*)ob;
  u16* Wt   = (u16*)(ob + (size_t)(16u << 20));

  bool fused = ws_size >= ((size_t)(64u << 20) + (size_t)(4u << 20));
  float* Sw = fused ? (float*)(ws + (size_t)(64u << 20))
                    : (float*)(ob + (size_t)(24u << 20));  // fallback: consumed pre-attn

  k_cvt_x<<<8192, 256, 0, stream>>>(X, Xb);
  k_cvt_w<<<dim3(50, 16), 256, 0, stream>>>(Wq, Wk, Wv, Ws, Wt);
  k_gemm<<<1600, 512, 0, stream>>>(Xb, Wt, bq, bk, bv, bs, Qw, Kw, Vw, Sw);
  if (!fused) k_scale_q<<<4096, 256, 0, stream>>>(Qw, Sw);
  k_trans_v<<<dim3(32, 64), 256, 0, stream>>>(Vw, Vt);
  k_attn<<<dim3(64, 8), 256, 0, stream>>>(Qw, Kw, Vt, fused ? Sw : nullptr, out);
}

// Round 17
// 162.740 us; speedup vs baseline: 1.1836x; 1.1099x over previous
//
#include <hip/hip_runtime.h>
#include <hip/hip_bf16.h>
#include <stdint.h>

typedef short bf16x8 __attribute__((ext_vector_type(8)));
typedef float f32x4 __attribute__((ext_vector_type(4)));
typedef unsigned short u16;
typedef unsigned short u16x4 __attribute__((ext_vector_type(4)));
typedef unsigned short u16x8 __attribute__((ext_vector_type(8)));
typedef unsigned int u32x4v __attribute__((ext_vector_type(4)));

#define LOG2E 1.44269504088896f

// sizes
#define Bz 4
#define Sz 2048
#define Hz 1024
#define NHz 16
#define HDz 64

__device__ __forceinline__ u16 f2bf(float f) {
  uint32_t u = __builtin_bit_cast(uint32_t, f);
  u += 0x7fffu + ((u >> 16) & 1u);
  return (u16)(u >> 16);
}
__device__ __forceinline__ float bf2f(u16 h) {
  uint32_t u = ((uint32_t)h) << 16;
  return __builtin_bit_cast(float, u);
}

__device__ __forceinline__ void gll16(const void* g, void* l) {
  __builtin_amdgcn_global_load_lds((const __attribute__((address_space(1))) void*)g,
                                   (__attribute__((address_space(3))) void*)l,
                                   16, 0, 0);
}

// ---------------- X (f32) -> bf16 ----------------
__global__ void k_cvt_x(const float* __restrict__ X, u16* __restrict__ Xb) {
  int i = blockIdx.x * 256 + threadIdx.x;
  float4 v = ((const float4*)X)[i];
  u16x4 r;
  r[0] = f2bf(v.x); r[1] = f2bf(v.y); r[2] = f2bf(v.z); r[3] = f2bf(v.w);
  ((u16x4*)Xb)[i] = r;
}

// ------- pack & transpose [Wq|Wk|Wv|Ws] -> Wt[3200][1024] bf16 -------
__global__ void k_cvt_w(const float* __restrict__ Wq, const float* __restrict__ Wk,
                        const float* __restrict__ Wv, const float* __restrict__ Ws,
                        u16* __restrict__ Wt) {
  __shared__ float tile[64][65];
  int n0 = blockIdx.x * 64, k0 = blockIdx.y * 64;
  const float* src; int ld, c0;
  if (n0 < 1024)      { src = Wq; ld = 1024; c0 = n0; }
  else if (n0 < 2048) { src = Wk; ld = 1024; c0 = n0 - 1024; }
  else if (n0 < 3072) { src = Wv; ld = 1024; c0 = n0 - 2048; }
  else                { src = Ws; ld = 128;  c0 = n0 - 3072; }
  int t = threadIdx.x;
  #pragma unroll
  for (int i = 0; i < 16; ++i) {
    int idx = t + i * 256; int r = idx >> 6, c = idx & 63;
    tile[r][c] = src[(size_t)(k0 + r) * ld + c0 + c];
  }
  __syncthreads();
  #pragma unroll
  for (int i = 0; i < 16; ++i) {
    int idx = t + i * 256; int rn = idx >> 6, ck = idx & 63;
    Wt[(size_t)(n0 + rn) * 1024 + k0 + ck] = f2bf(tile[ck][rn]);
  }
}

// ---------------- fused QKV+S GEMM: [8192,1024] x [1024,3200] ----------------
// 128x128 tile, BK=64, single-buffer 32KB LDS; 512 thr (2Mx4N waves);
// XCD-aware bijective mapping. BEST MEASURED CONFIG (R11/R15: 96us).
// Epilogue fuses the V transpose: V written directly to Vt[bh][d][s] as
// packed u16x4 (4 consecutive si per fragment) -> k_trans_v deleted.
__launch_bounds__(512, 6)
__global__ void k_gemm(const u16* __restrict__ Xb, const u16* __restrict__ Wt,
                       const float* __restrict__ bq, const float* __restrict__ bk,
                       const float* __restrict__ bv, const float* __restrict__ bs,
                       u16* __restrict__ Qw, u16* __restrict__ Kw, u16* __restrict__ Vt,
                       float* __restrict__ Sw) {
  __shared__ u16 As[128 * 64];   // 16KB
  __shared__ u16 Bs[128 * 64];
  int t = threadIdx.x, lane = t & 63;
  int l15 = lane & 15, g = lane >> 4;
  int wave = t >> 6, wr = wave >> 2, wc = wave & 3;

  int p = blockIdx.x;
  int xcd = p & 7;
  int idx = p >> 3;            // 0..199
  int n_t = idx >> 3;          // 0..24
  int m_t = xcd * 8 + (idx & 7);
  int m0 = m_t * 128, n0 = n_t * 128;

  f32x4 acc[4][2];
  #pragma unroll
  for (int i = 0; i < 4; ++i)
    #pragma unroll
    for (int j = 0; j < 2; ++j) { f32x4 z = {0.f,0.f,0.f,0.f}; acc[i][j] = z; }

  int srow = t >> 3;               // 0..63
  int sob  = (t & 7) << 4;         // 0..112

  const char* Ag = (const char*)Xb;
  const char* Bg = (const char*)Wt;

  {
    int row = srow;
    int sb = sob ^ ((row & 7) << 4);
    gll16(Ag + (size_t)(m0 + row) * 2048 + sb, (char*)As + row * 128 + sob);
    gll16(Bg + (size_t)(n0 + row) * 2048 + sb, (char*)Bs + row * 128 + sob);
    row = 64 + srow;
    sb = sob ^ ((row & 7) << 4);
    gll16(Ag + (size_t)(m0 + row) * 2048 + sb, (char*)As + row * 128 + sob);
    gll16(Bg + (size_t)(n0 + row) * 2048 + sb, (char*)Bs + row * 128 + sob);
  }
  __syncthreads();

  for (int kt = 0; kt < 16; ++kt) {
    #pragma unroll
    for (int ksub = 0; ksub < 2; ++ksub) {
      bf16x8 af[4], bfr[2];
      #pragma unroll
      for (int ai = 0; ai < 4; ++ai) {
        int row = wr * 64 + ai * 16 + l15;
        af[ai] = *(const bf16x8*)((const char*)As + row * 128 +
                                  ((ksub * 64 + 16 * g) ^ ((row & 7) << 4)));
      }
      #pragma unroll
      for (int bj = 0; bj < 2; ++bj) {
        int row = wc * 32 + bj * 16 + l15;
        bfr[bj] = *(const bf16x8*)((const char*)Bs + row * 128 +
                                   ((ksub * 64 + 16 * g) ^ ((row & 7) << 4)));
      }
      #pragma unroll
      for (int ai = 0; ai < 4; ++ai)
        #pragma unroll
        for (int bj = 0; bj < 2; ++bj)
          acc[ai][bj] = __builtin_amdgcn_mfma_f32_16x16x32_bf16(af[ai], bfr[bj], acc[ai][bj], 0, 0, 0);
    }
    if (kt + 1 < 16) {
      __syncthreads();
      size_t kb = (size_t)(kt + 1) * 128;
      int row = srow;
      int sb = sob ^ ((row & 7) << 4);
      gll16(Ag + (size_t)(m0 + row) * 2048 + kb + sb, (char*)As + row * 128 + sob);
      gll16(Bg + (size_t)(n0 + row) * 2048 + kb + sb, (char*)Bs + row * 128 + sob);
      row = 64 + srow;
      sb = sob ^ ((row & 7) << 4);
      gll16(Ag + (size_t)(m0 + row) * 2048 + kb + sb, (char*)As + row * 128 + sob);
      gll16(Bg + (size_t)(n0 + row) * 2048 + kb + sb, (char*)Bs + row * 128 + sob);
      __syncthreads();
    }
  }

  #pragma unroll
  for (int ai = 0; ai < 4; ++ai) {
    #pragma unroll
    for (int bj = 0; bj < 2; ++bj) {
      int mb = m0 + wr * 64 + ai * 16 + ((lane >> 4) << 2);   // r=0 row; mb%4==0
      int j  = n0 + wc * 32 + bj * 16 + l15;
      int b  = mb >> 11, si0 = mb & 2047;
      if (j < 2048) {
        // Q or K: per-element scattered stores (layout [bh][s][d])
        const float* bias = (j < 1024) ? bq : bk;
        int jj = j & 1023, h = jj >> 6, d = jj & 63;
        u16* dstb = (j < 1024) ? Qw : Kw;
        float bv0 = bias[jj];
        #pragma unroll
        for (int r = 0; r < 4; ++r) {
          float v = acc[ai][bj][r] + bv0;
          dstb[(((size_t)(b * NHz + h) * Sz + si0 + r) << 6) + d] = f2bf(v);
        }
      } else if (j < 3072) {
        // V: write TRANSPOSED to Vt[bh][d][s]; 4 consecutive si -> one u16x4
        int jj = j - 2048, h = jj >> 6, d = jj & 63;
        float bv0 = bv[jj];
        u16x4 pk;
        #pragma unroll
        for (int r = 0; r < 4; ++r) pk[r] = f2bf(acc[ai][bj][r] + bv0);
        *(u16x4*)(Vt + ((size_t)(b * NHz + h) * 64 + d) * Sz + si0) = pk;
      } else {
        // scale head -> Sw
        int c = j - 3072;
        float bs0 = bs[c];
        #pragma unroll
        for (int r = 0; r < 4; ++r) {
          float v = acc[ai][bj][r] + bs0;
          float sig = 1.0f / (1.0f + __expf(-v));
          // fold softmax 1/sqrt(64) AND log2(e) (exp->exp2 domain) into Q scale
          Sw[(size_t)(mb + r) * 128 + c] = (0.9f + 0.2f * sig) * 0.125f * LOG2E;
        }
      }
    }
  }
}

// ---------------- fallback: Q *= s (only if ws can't hold Sw) ----------------
__global__ void k_scale_q(u16* __restrict__ Qw, const float* __restrict__ Sw) {
  int tid = blockIdx.x * 256 + threadIdx.x;
  size_t base = (size_t)tid * 8;
  int bh = (int)(base >> 17);
  int si = (int)((base >> 6) & 2047);
  int d0 = (int)(base & 63);
  int b = bh >> 4, h = bh & 15;
  float s = Sw[((size_t)(b * Sz + si)) * 128 + h * 8 + (d0 >> 3)];
  u16x8 v = *(u16x8*)(Qw + base);
  #pragma unroll
  for (int j = 0; j < 8; ++j) v[j] = f2bf(bf2f(v[j]) * s);
  *(u16x8*)(Qw + base) = v;
}

// ---------------- attention: qi=4 (QBLK=64/wave) + in-register P (T12) ----------------
// grid (64 bh, 8 q-blocks of 256). 4 waves x 64 q-rows; KVBLK=64, dbuf K/V (32KB).
// Swapped QK^T with pi-permuted K rows; exp2 no-max; P C->A relayout fully
// in-register via cvt_pk + v_permlane32_swap_b32; row-sums via ones-MFMA.
__launch_bounds__(256)
__global__ void k_attn(const u16* __restrict__ Qw, const u16* __restrict__ Kw,
                       const u16* __restrict__ Vt, const float* __restrict__ Swp,
                       float* __restrict__ out) {
  __shared__ u16 Kl[2][64 * 64];   // 16KB
  __shared__ u16 Vl[2][64 * 64];   // 16KB

  int t = threadIdx.x, lane = t & 63, wave = t >> 6;
  int l15 = lane & 15, g = lane >> 4;
  int bh = blockIdx.x, b = bh >> 4, h = bh & 15;
  int q0 = blockIdx.y * 256 + wave * 64;

  const u16* Qb = Qw + (size_t)bh * Sz * 64;
  const char* Kg = (const char*)(Kw + (size_t)bh * Sz * 64);
  const char* Vg = (const char*)(Vt + (size_t)bh * 64 * Sz);

  // pi(l15): swap bits 2 and 3 (loop-invariant)
  int pi15 = (l15 & 3) | ((l15 & 4) << 1) | ((l15 & 8) >> 1);

  int srow = t >> 3;               // 0..31
  int sobyte = (t & 7) << 4;       // 0..112

  bf16x8 qf[4][2];
  #pragma unroll
  for (int qi = 0; qi < 4; ++qi)
    #pragma unroll
    for (int ks = 0; ks < 2; ++ks)
      qf[qi][ks] = *(const bf16x8*)(Qb + (size_t)(q0 + 16 * qi + l15) * 64 + 32 * ks + 8 * g);
  if (Swp) {
    #pragma unroll
    for (int qi = 0; qi < 4; ++qi) {
      size_t m = (size_t)(b * Sz + q0 + 16 * qi + l15);
      #pragma unroll
      for (int ks = 0; ks < 2; ++ks) {
        float s = Swp[m * 128 + h * 8 + 4 * ks + g];
        bf16x8 q = qf[qi][ks];
        #pragma unroll
        for (int j = 0; j < 8; ++j) q[j] = (short)f2bf(bf2f((u16)q[j]) * s);
        qf[qi][ks] = q;
      }
    }
  }

  bf16x8 ones;
  #pragma unroll
  for (int j = 0; j < 8; ++j) ones[j] = (short)0x3F80;

  f32x4 o[4][4], lacc[4];
  #pragma unroll
  for (int qi = 0; qi < 4; ++qi) {
    f32x4 z = {0.f,0.f,0.f,0.f};
    lacc[qi] = z;
    #pragma unroll
    for (int nt = 0; nt < 4; ++nt) o[qi][nt] = z;
  }

  // prologue: stage tile 0 into buf 0 (4 gll16/thread)
  #pragma unroll
  for (int c = 0; c < 2; ++c) {
    int row = c * 32 + srow;
    int sw2 = (row & 7) << 4;
    gll16(Kg + (size_t)row * 128 + (sobyte ^ sw2), (char*)Kl[0] + row * 128 + sobyte);
    gll16(Vg + (size_t)row * (Sz * 2) + (sobyte ^ sw2), (char*)Vl[0] + row * 128 + sobyte);
  }
  __syncthreads();

  int cur = 0;
  for (int kv0 = 0; kv0 < Sz; kv0 += 64) {
    if (kv0 + 64 < Sz) {
      int nxt = cur ^ 1, kvn = kv0 + 64;
      #pragma unroll
      for (int c = 0; c < 2; ++c) {
        int row = c * 32 + srow;
        int sw2 = (row & 7) << 4;
        gll16(Kg + (size_t)(kvn + row) * 128 + (sobyte ^ sw2),
              (char*)Kl[nxt] + row * 128 + sobyte);
        gll16(Vg + (size_t)row * (Sz * 2) + (size_t)kvn * 2 + (sobyte ^ sw2),
              (char*)Vl[nxt] + row * 128 + sobyte);
      }
    }
    const char* Kb = (const char*)Kl[cur];
    const char* Vb = (const char*)Vl[cur];

    // ---- per qi-pair: QK^T (swapped, pi-permuted) + exp2 + in-reg relayout ----
    bf16x8 pa[4][2];
    #pragma unroll
    for (int qp = 0; qp < 2; ++qp) {
      f32x4 sc[2][4];
      __builtin_amdgcn_s_setprio(1);
      #pragma unroll
      for (int nt = 0; nt < 4; ++nt) {
        int row = 16 * nt + pi15;
        int sw2 = (row & 7) << 4;
        bf16x8 kf0 = *(const bf16x8*)(Kb + row * 128 + ((16 * g) ^ sw2));
        bf16x8 kf1 = *(const bf16x8*)(Kb + row * 128 + ((64 + 16 * g) ^ sw2));
        #pragma unroll
        for (int j = 0; j < 2; ++j) {
          f32x4 a = {0.f,0.f,0.f,0.f};
          a = __builtin_amdgcn_mfma_f32_16x16x32_bf16(kf0, qf[2 * qp + j][0], a, 0, 0, 0);
          a = __builtin_amdgcn_mfma_f32_16x16x32_bf16(kf1, qf[2 * qp + j][1], a, 0, 0, 0);
          sc[j][nt] = a;
        }
      }
      __builtin_amdgcn_s_setprio(0);
      #pragma unroll
      for (int j = 0; j < 2; ++j) {
        unsigned W0[4], W1[4];
        #pragma unroll
        for (int nt = 0; nt < 4; ++nt) {
          float p0 = __builtin_amdgcn_exp2f(sc[j][nt][0]);
          float p1 = __builtin_amdgcn_exp2f(sc[j][nt][1]);
          float p2 = __builtin_amdgcn_exp2f(sc[j][nt][2]);
          float p3 = __builtin_amdgcn_exp2f(sc[j][nt][3]);
          asm("v_cvt_pk_bf16_f32 %0, %1, %2" : "=v"(W0[nt]) : "v"(p0), "v"(p1));
          asm("v_cvt_pk_bf16_f32 %0, %1, %2" : "=v"(W1[nt]) : "v"(p2), "v"(p3));
        }
        #pragma unroll
        for (int ks = 0; ks < 2; ++ks) {
          unsigned x0 = W0[2 * ks], y0 = W0[2 * ks + 1];
          unsigned x1 = W1[2 * ks], y1 = W1[2 * ks + 1];
          // dst' = {dst.row0, src.row0}; src' = {dst.row1, src.row1}
          asm("v_permlane32_swap_b32 %0, %1" : "+v"(x0), "+v"(y0));
          asm("v_permlane32_swap_b32 %0, %1" : "+v"(x1), "+v"(y1));
          u32x4v wv; wv[0] = x0; wv[1] = x1; wv[2] = y0; wv[3] = y1;
          pa[2 * qp + j][ks] = __builtin_bit_cast(bf16x8, wv);
        }
      }
    }

    // ---- PV + row-sum: single pass, vf read once per (ks,nt) ----
    __builtin_amdgcn_s_setprio(1);
    #pragma unroll
    for (int ks = 0; ks < 2; ++ks) {
      #pragma unroll
      for (int qi = 0; qi < 4; ++qi)
        lacc[qi] = __builtin_amdgcn_mfma_f32_16x16x32_bf16(pa[qi][ks], ones, lacc[qi], 0, 0, 0);
      #pragma unroll
      for (int nt = 0; nt < 4; ++nt) {
        int row = 16 * nt + l15;
        int sw2 = (row & 7) << 4;
        bf16x8 vf = *(const bf16x8*)(Vb + row * 128 + ((64 * ks + 16 * g) ^ sw2));
        #pragma unroll
        for (int qi = 0; qi < 4; ++qi)
          o[qi][nt] = __builtin_amdgcn_mfma_f32_16x16x32_bf16(pa[qi][ks], vf, o[qi][nt], 0, 0, 0);
      }
    }
    __builtin_amdgcn_s_setprio(0);
    __syncthreads();
    cur ^= 1;
  }

  // ---- epilogue: out = o / rowsum (lacc has same C-layout as o) ----
  #pragma unroll
  for (int qi = 0; qi < 4; ++qi) {
    #pragma unroll
    for (int r = 0; r < 4; ++r) {
      float inv = 1.0f / lacc[qi][r];
      #pragma unroll
      for (int nt = 0; nt < 4; ++nt)
        out[((size_t)(b * Sz + q0 + 16 * qi + 4 * g + r)) * (NHz * HDz) +
            h * 64 + 16 * nt + l15] = o[qi][nt][r] * inv;
    }
  }
}

extern "C" void kernel_launch(void* const* d_in, const int* in_sizes, int n_in,
                              void* d_out, int out_size, void* d_ws, size_t ws_size,
                              hipStream_t stream) {
  const float* X  = (const float*)d_in[0];
  const float* Wq = (const float*)d_in[1];
  const float* bq = (const float*)d_in[2];
  const float* Wk = (const float*)d_in[3];
  const float* bk = (const float*)d_in[4];
  const float* Wv = (const float*)d_in[5];
  const float* bv = (const float*)d_in[6];
  const float* Ws = (const float*)d_in[7];
  const float* bs = (const float*)d_in[8];
  float* out = (float*)d_out;

  // ws: Qw | Kw | Vt (16 MB each; V written transposed by k_gemm) [+ Sw if room]
  char* ws = (char*)d_ws;
  u16* Qw = (u16*)(ws);
  u16* Kw = (u16*)(ws + (size_t)(16u << 20));
  u16* Vt = (u16*)(ws + (size_t)(32u << 20));

  // d_out scratch: Xb (16MB) | Wt (6.55MB) — consumed by k_gemm before attn writes.
  char* ob = (char*)d_out;
  u16* Xb   = (u16*)ob;
  u16* Wt   = (u16*)(ob + (size_t)(16u << 20));

  bool fused = ws_size >= ((size_t)(64u << 20) + (size_t)(4u << 20));
  float* Sw = fused ? (float*)(ws + (size_t)(64u << 20))
                    : (float*)(ob + (size_t)(24u << 20));  // fallback: consumed pre-attn

  k_cvt_x<<<8192, 256, 0, stream>>>(X, Xb);
  k_cvt_w<<<dim3(50, 16), 256, 0, stream>>>(Wq, Wk, Wv, Ws, Wt);
  k_gemm<<<1600, 512, 0, stream>>>(Xb, Wt, bq, bk, bv, bs, Qw, Kw, Vt, Sw);
  if (!fused) k_scale_q<<<4096, 256, 0, stream>>>(Qw, Sw);
  k_attn<<<dim3(64, 8), 256, 0, stream>>>(Qw, Kw, Vt, fused ? Sw : nullptr, out);
}